// Round 5
// baseline (261.761 us; speedup 1.0000x reference)
//
#include <hip/hip_runtime.h>

// ---------------------------------------------------------------------------
// QuantizedShaper: B=256, L=8192, DIM=256, NPAT=64, HIST=32, WIN=8, T=1024.
//
//   scores r_t[p] = clip( sum_h xpad[t*8+h] * W2[p,h] + bias2[p], 0, 6 )
//   argmax(score - av) == argmax( U_t - cnt ),  U_t = r_t - av0 + t/64
//   out[b, t*8+w] = relu( shapes_w[w, idx[t,b]] - x[b, t*8+w] )
//
// R5 scan: count-space + 1-step lookahead. Butterfly = single-pass top-2
// (M,S) in ordkey-uint domain on the UNPATCHED base z = U - cnt_prev
// (depends only on step i-1 -> pipelines under resolve(i)). Resolution is
// SALU-only on ballots E1/E2/GT/GE; pending-winner lane tested via bit
// shift (no dynamic readlane). Winners packed 6b into SGPRs per chunk.
// ---------------------------------------------------------------------------

constexpr int Bb = 256, Ll = 8192, DIMc = 256, NPAT = 64, HIST = 32, WINc = 8;
constexpr int Tt = Ll / WINc;   // 1024
constexpr int TC = 32;          // t-chunk
constexpr int NC = Tt / TC;     // 32 chunks
constexpr float CINV = 1.0f / 64.0f;

__device__ __forceinline__ unsigned ordk(float v) {
  int b = __float_as_int(v);
  return (unsigned)(b ^ ((b >> 31) | 0x80000000));
}

#define DPPI(x, ctrl) \
  ((unsigned)__builtin_amdgcn_update_dpp((int)(x), (int)(x), (ctrl), 0xF, 0xF, false))

// one top-2 merge stage: (M,S) <- merge((M,S), dpp(M,S))
#define TOP2_STAGE(M, S, ctrl)                    \
  do {                                            \
    unsigned _Md = DPPI(M, ctrl);                 \
    unsigned _Sd = DPPI(S, ctrl);                 \
    unsigned _mn = (M) < _Md ? (M) : _Md;         \
    (M) = (M) > _Md ? (M) : _Md;                  \
    (S) = (S) > _Sd ? (S) : _Sd;                  \
    (S) = (S) > _mn ? (S) : _mn;                  \
  } while (0)

#define DPP_ADDF(s, ctrl, rmask)                                               \
  do {                                                                         \
    int _si = __float_as_int(s);                                               \
    int _ti = __builtin_amdgcn_update_dpp(_si, _si, (ctrl), (rmask), 0xF, false); \
    (s) += __int_as_float(_ti);                                                \
  } while (0)

struct BalSet {
  unsigned long long E1, E2, GT, GE;
};

// one block per pattern p: W2[p,0..31] + bias2[p]
__global__ __launch_bounds__(256) void precompute_kernel(
    const float* __restrict__ conv_w, const float* __restrict__ conv_b,
    const float* __restrict__ keys_w, float* __restrict__ wsf) {
  __shared__ float part[8][32];
  __shared__ float bred[4];
  const int p = blockIdx.x;
  const int t = threadIdx.x;
  const int h = t & 31, g = t >> 5;
  const float* kwp = keys_w + (size_t)p * DIMc;

  float acc = 0.f;
#pragma unroll
  for (int dd = 0; dd < 32; ++dd) {
    int d = g * 32 + dd;
    acc = fmaf(kwp[d], conv_w[d * HIST + h], acc);
  }
  part[g][h] = acc;

  float bp = kwp[t] * conv_b[t];
#pragma unroll
  for (int off = 32; off; off >>= 1) bp += __shfl_down(bp, off);
  if ((t & 63) == 0) bred[t >> 6] = bp;
  __syncthreads();

  if (t < 32) {
    float s = 0.f;
#pragma unroll
    for (int gg = 0; gg < 8; ++gg) s += part[gg][t];
    wsf[(t >> 2) * (NPAT * 4) + p * 4 + (t & 3)] = s;  // float4-friendly
  } else if (t == 32) {
    wsf[NPAT * HIST + p] = (bred[0] + bred[1]) + (bred[2] + bred[3]);
  }
}

__global__ __launch_bounds__(256) void shaper_kernel(
    const float* __restrict__ x, const float* __restrict__ avg_init,
    const float* __restrict__ shapes_w, const float* __restrict__ wsf,
    float* __restrict__ out) {
  __shared__ __align__(16) float xpad[HIST - 1 + Ll + 1];
  __shared__ float scb[2][TC * NPAT];
  __shared__ int   idxb[Tt];
  __shared__ float shp[WINc * NPAT];

  const int b    = blockIdx.x;
  const int tid  = threadIdx.x;
  const int wid  = tid >> 6;
  const int lane = tid & 63;
  const float* xrow = x + (size_t)b * Ll;

  // ---- stage x (left-padded) + shapes into LDS ----
  if (tid < HIST - 1) xpad[tid] = 0.f;
  {
    const float4* xv4 = (const float4*)xrow;
#pragma unroll
    for (int k = 0; k < 8; ++k) {
      int i4 = k * 256 + tid;
      float4 v = xv4[i4];
      float* dst = xpad + HIST - 1 + i4 * 4;
      dst[0] = v.x; dst[1] = v.y; dst[2] = v.z; dst[3] = v.w;
    }
  }
  for (int i = tid; i < WINc * NPAT; i += 256) shp[i] = shapes_w[i];

  // ---- av0 (fill waves only; identical butterfly in each wave => bit-same)
  float av0 = 0.f;
  {
    float s = avg_init[(size_t)b * NPAT + lane];
    float t = s;
    DPP_ADDF(t, 0xB1, 0xF);
    DPP_ADDF(t, 0x4E, 0xF);
    DPP_ADDF(t, 0x141, 0xF);
    DPP_ADDF(t, 0x140, 0xF);   // row16 sums
    DPP_ADDF(t, 0x142, 0xA);   // bcast15 -> rows 1,3
    DPP_ADDF(t, 0x143, 0xC);   // bcast31 -> rows 2,3; lane63 = total
    float tot = __int_as_float(__builtin_amdgcn_readlane(__float_as_int(t), 63));
    av0 = s - tot * CINV;
  }

  // ---- per-role setup ----
  float4 w2v[8];
  float  b2 = 0.f;
  if (wid > 0) {
    const float4* w2g = (const float4*)wsf;
#pragma unroll
    for (int h4 = 0; h4 < 8; ++h4) w2v[h4] = w2g[h4 * 64 + lane];
    b2 = wsf[NPAT * HIST + lane];
  }
  __syncthreads();

  // fill chunk c: sb[t][p] = (relu6(score) - av0[p]) + tglob/64   (== U_t[p])
  auto fill = [&](int c, float* __restrict__ sb) {
    int base = c * TC;
    for (int tl = wid - 1; tl < TC; tl += 3) {
      int t = base + tl;
      const float4* xw = (const float4*)(xpad + t * WINc);  // 32B-aligned
      float acc = b2;
#pragma unroll
      for (int h4 = 0; h4 < 8; ++h4) {
        float4 xv = xw[h4];
        float4 wv = w2v[h4];
        acc = fmaf(xv.x, wv.x, acc);
        acc = fmaf(xv.y, wv.y, acc);
        acc = fmaf(xv.z, wv.z, acc);
        acc = fmaf(xv.w, wv.w, acc);
      }
      float sc = fminf(fmaxf(acc, 0.f), 6.f);
      sb[tl * NPAT + lane] = (sc - av0) + (float)t * CINV;
    }
  };

  // ---- scan state (wave 0) ----
  float cnt = 0.f;                 // per-lane win count
  int   wp  = -1;                  // pending winner (applied to cnt next step)
  unsigned long long m_w = 0;      // mask of pending winner (0 = none)
  const float vone = 1.0f;

  // build ballots for a base-z step (top-2 butterfly in ordkey domain)
  auto mkb = [&](float zv) {
    BalSet B;
    float z1 = zv - vone;          // candidate value of the pending lane
    unsigned zu = ordk(zv);
    unsigned M = zu, S = 0u;       // S=0 == -inf sentinel in ordkey domain
    TOP2_STAGE(M, S, 0xB1);        // xor1
    TOP2_STAGE(M, S, 0x4E);        // xor2
    TOP2_STAGE(M, S, 0x141);       // xor4 (row_half_mirror)
    TOP2_STAGE(M, S, 0x140);       // xor8 (row_mirror) -> per-row16 top-2
    unsigned M0 = (unsigned)__builtin_amdgcn_readlane((int)M, 0);
    unsigned M1 = (unsigned)__builtin_amdgcn_readlane((int)M, 16);
    unsigned M2 = (unsigned)__builtin_amdgcn_readlane((int)M, 32);
    unsigned M3 = (unsigned)__builtin_amdgcn_readlane((int)M, 48);
    unsigned S0 = (unsigned)__builtin_amdgcn_readlane((int)S, 0);
    unsigned S1 = (unsigned)__builtin_amdgcn_readlane((int)S, 16);
    unsigned S2 = (unsigned)__builtin_amdgcn_readlane((int)S, 32);
    unsigned S3 = (unsigned)__builtin_amdgcn_readlane((int)S, 48);
    // scalar merge of 4 (M,S) pairs
    unsigned h1 = M0 > M1 ? M0 : M1, l1 = M0 < M1 ? M0 : M1;
    unsigned h2 = M2 > M3 ? M2 : M3, l2 = M2 < M3 ? M2 : M3;
    unsigned Mu = h1 > h2 ? h1 : h2;
    unsigned sa = h1 < h2 ? h1 : h2;          // min of pair-maxes
    unsigned sb_ = l1 > l2 ? l1 : l2;         // max of pair-mins
    unsigned secM = sa > sb_ ? sa : sb_;      // 2nd of {M0..M3}
    unsigned sr = S0 > S1 ? S0 : S1;
    unsigned sr2 = S2 > S3 ? S2 : S3;
    unsigned Smax = sr > sr2 ? sr : sr2;
    unsigned Su = Smax > secM ? Smax : secM;  // global second max
    // inverse ordkey -> float bits of S
    unsigned sbits = (Su >= 0x80000000u) ? (Su ^ 0x80000000u) : ~Su;
    float Sf = __int_as_float((int)sbits);
    B.E1 = __ballot(zu == Mu);
    B.E2 = __ballot(zu == Su);
    B.GT = __ballot(z1 > Sf);
    B.GE = __ballot(z1 >= Sf);
    return B;
  };

  auto scan_chunk = [&](const float* __restrict__ sb, int tbase) {
    float r[TC];
#pragma unroll
    for (int i = 0; i < TC; ++i) r[i] = sb[i * NPAT + lane];
    unsigned long long sa0 = 0, sa1 = 0, sa2 = 0, sa3 = 0;  // packed winners
    BalSet B = mkb(r[0] - cnt);    // chunk prologue: base complete, m_w==0
#pragma unroll
    for (int i = 0; i < TC; ++i) {
      // ---- resolve step tbase+i (SALU only) ----
      unsigned long long b1x = B.E1 & ~m_w;
      int jA  = __ffsll(b1x) - 1;
      int jB1 = __ffsll(B.E2) - 1;
      int wq  = wp & 63;
      int gt  = (int)((B.GT >> wq) & 1);
      int ge  = (int)((B.GE >> wq) & 1);
      int jmn = wp < jB1 ? wp : jB1;
      int wB  = gt ? wp : (ge ? jmn : jB1);
      int w   = b1x ? jA : wB;
      // pack winner (compile-time slot selection under unroll)
      if (i < 10)      sa0 |= (unsigned long long)w << (6 * i);
      else if (i < 20) sa1 |= (unsigned long long)w << (6 * (i - 10));
      else if (i < 30) sa2 |= (unsigned long long)w << (6 * (i - 20));
      else             sa3 |= (unsigned long long)w << (6 * (i - 30));
      // ---- apply previous pending winner to cnt ----
      cnt += (lane == wp) ? 1.0f : 0.0f;
      // ---- advance pending state ----
      wp  = w;
      m_w = 1ull << w;
      // ---- lookahead: ballots for step i+1 on base missing only w ----
      if (i + 1 < TC) B = mkb(r[i + 1] - cnt);
    }
    // chunk epilogue: fold last pending winner; clear pending
    cnt += (lane == wp) ? 1.0f : 0.0f;
    wp  = -1;
    m_w = 0;
    // unpack winners -> idxb
    unsigned long long src = (lane < 10) ? sa0 : (lane < 20) ? sa1
                           : (lane < 30) ? sa2 : sa3;
    int sh = 6 * (lane - ((lane < 10) ? 0 : (lane < 20) ? 10
                          : (lane < 30) ? 20 : 30));
    int widx = (int)((src >> sh) & 63);
    if (lane < TC) idxb[tbase + lane] = widx;
  };

  // ---- pipeline: wave0 scans chunk c, waves1-3 fill chunk c+1 ----
  if (wid > 0) fill(0, scb[0]);
  __syncthreads();

  for (int c = 0; c < NC; ++c) {
    if (wid == 0) {
      scan_chunk(scb[c & 1], c * TC);
    } else if (c + 1 < NC) {
      fill(c + 1, scb[(c + 1) & 1]);
    }
    __syncthreads();
  }

  // ---- epilogue: out[b,l] = relu(shapes[l&7, idx[l>>3]] - x[b,l]) ----
  float4* outv = (float4*)(out + (size_t)b * Ll);
#pragma unroll
  for (int k = 0; k < 8; ++k) {
    int i4 = k * 256 + tid;
    int l0 = i4 * 4;
    int t  = l0 >> 3;
    int w0 = l0 & 7;
    int p  = idxb[t];
    float4 o;
    o.x = fmaxf(shp[(w0 + 0) * NPAT + p] - xpad[HIST - 1 + l0 + 0], 0.f);
    o.y = fmaxf(shp[(w0 + 1) * NPAT + p] - xpad[HIST - 1 + l0 + 1], 0.f);
    o.z = fmaxf(shp[(w0 + 2) * NPAT + p] - xpad[HIST - 1 + l0 + 2], 0.f);
    o.w = fmaxf(shp[(w0 + 3) * NPAT + p] - xpad[HIST - 1 + l0 + 3], 0.f);
    outv[i4] = o;
  }
}

extern "C" void kernel_launch(void* const* d_in, const int* in_sizes, int n_in,
                              void* d_out, int out_size, void* d_ws, size_t ws_size,
                              hipStream_t stream) {
  const float* x        = (const float*)d_in[0];
  const float* avg_init = (const float*)d_in[1];
  const float* conv_w   = (const float*)d_in[2];
  const float* conv_b   = (const float*)d_in[3];
  const float* keys_w   = (const float*)d_in[4];
  const float* shapes_w = (const float*)d_in[5];
  float* wsf = (float*)d_ws;

  precompute_kernel<<<NPAT, 256, 0, stream>>>(conv_w, conv_b, keys_w, wsf);
  shaper_kernel<<<Bb, 256, 0, stream>>>(x, avg_init, shapes_w, wsf,
                                        (float*)d_out);
}